// Round 1
// baseline (464.732 us; speedup 1.0000x reference)
//
#include <hip/hip_runtime.h>
#include <hip/hip_bf16.h>
#include <climits>

// Problem constants (fixed by setup_inputs)
#define BATCH 16
#define NCH 3
#define H 512
#define W 512
#define HW (H * W)          // 262144 = 2^18
#define PAD 7
#define WIN 15
#define K 26                // int(0.0001 * 512 * 512)
#define CHUNK 2048
#define CHUNKS (HW / CHUNK) // 128
#define NCAND (CHUNKS * K)  // 3328
#define BK (BATCH * K)      // 416

#define FINF __builtin_inff()

// ---------------------------------------------------------------------------
// K1: horizontal 15-wide max & min pool per row (same padding, pad ignored)
// one block per row of B*3*H rows
__global__ __launch_bounds__(256) void hpool_kernel(
    const float* __restrict__ x, float* __restrict__ hmax, float* __restrict__ hmin) {
    int row = blockIdx.x; // 0 .. BATCH*NCH*H-1
    const float* rp = x + (size_t)row * W;
    __shared__ float smax[W + WIN - 1];
    __shared__ float smin[W + WIN - 1];
    for (int i = threadIdx.x; i < W + WIN - 1; i += blockDim.x) {
        int xx = i - PAD;
        bool in = (xx >= 0) && (xx < W);
        float v = in ? rp[xx] : 0.0f;
        smax[i] = in ? v : -FINF;
        smin[i] = in ? v : FINF;
    }
    __syncthreads();
    for (int xo = threadIdx.x; xo < W; xo += blockDim.x) {
        float mx = smax[xo];
        float mn = smin[xo];
#pragma unroll
        for (int j = 1; j < WIN; ++j) {
            mx = fmaxf(mx, smax[xo + j]);
            mn = fminf(mn, smin[xo + j]);
        }
        hmax[(size_t)row * W + xo] = mx;
        hmin[(size_t)row * W + xo] = mn;
    }
}

// ---------------------------------------------------------------------------
// K2: vertical 15-tall pool + channel reduction.
// writes per-channel window-max Vmax (needed for t), and bc = max_c, dc = min_c
__global__ __launch_bounds__(256) void vpool_kernel(
    const float* __restrict__ hmax, const float* __restrict__ hmin,
    float* __restrict__ vmax, float* __restrict__ bc, float* __restrict__ dc) {
    int i = blockIdx.x * blockDim.x + threadIdx.x;
    if (i >= BATCH * HW) return;
    int b = i >> 18;          // / HW
    int p = i & (HW - 1);
    int y = p >> 9;           // / W
    int xx = p & (W - 1);
    int y0 = y - PAD; if (y0 < 0) y0 = 0;
    int y1 = y + PAD; if (y1 > H - 1) y1 = H - 1;
    float bcv = -FINF, dcv = FINF;
#pragma unroll
    for (int c = 0; c < NCH; ++c) {
        size_t cbase = ((size_t)(b * NCH + c)) << 18;
        float mx = -FINF, mn = FINF;
        for (int yy = y0; yy <= y1; ++yy) {
            size_t o = cbase + ((size_t)yy << 9) + xx;
            mx = fmaxf(mx, hmax[o]);
            mn = fminf(mn, hmin[o]);
        }
        vmax[cbase + p] = mx;
        bcv = fmaxf(bcv, mx);
        dcv = fminf(dcv, mn);
    }
    bc[i] = bcv;
    dc[i] = dcv;
}

// ---------------------------------------------------------------------------
// K3: per-(batch, chunk) exact top-K with jax.lax.top_k tie rule:
// order by key desc, then index asc. NEG=true selects smallest values.
template <bool NEG>
__global__ __launch_bounds__(256) void chunk_topk_kernel(
    const float* __restrict__ map, float* __restrict__ ckey, int* __restrict__ cidx) {
    int blk = blockIdx.x;
    int b = blk / CHUNKS;
    int ch = blk % CHUNKS;
    const float* mp = map + (size_t)b * HW + (size_t)ch * CHUNK;
    float key[8];
    int gid[8];
#pragma unroll
    for (int j = 0; j < 8; ++j) {
        int e = threadIdx.x + j * 256;
        float v = mp[e];
        key[j] = NEG ? -v : v;
        gid[j] = ch * CHUNK + e;
    }
    unsigned picked = 0;
    __shared__ float sk[256];
    __shared__ int si[256];
    float* okey = ckey + ((size_t)b * CHUNKS + ch) * K;
    int* oidx = cidx + ((size_t)b * CHUNKS + ch) * K;
    for (int r = 0; r < K; ++r) {
        float bk = -FINF;
        int bi = INT_MAX;
#pragma unroll
        for (int j = 0; j < 8; ++j) {
            if (!((picked >> j) & 1u)) {
                if (key[j] > bk || (key[j] == bk && gid[j] < bi)) { bk = key[j]; bi = gid[j]; }
            }
        }
        sk[threadIdx.x] = bk;
        si[threadIdx.x] = bi;
        __syncthreads();
        for (int s = 128; s > 0; s >>= 1) {
            if (threadIdx.x < s) {
                float ok = sk[threadIdx.x + s];
                int oi = si[threadIdx.x + s];
                if (ok > sk[threadIdx.x] || (ok == sk[threadIdx.x] && oi < si[threadIdx.x])) {
                    sk[threadIdx.x] = ok;
                    si[threadIdx.x] = oi;
                }
            }
            __syncthreads();
        }
        float wk = sk[0];
        int wi = si[0];
        if (threadIdx.x == 0) { okey[r] = wk; oidx[r] = wi; }
#pragma unroll
        for (int j = 0; j < 8; ++j)
            if (gid[j] == wi) picked |= 1u << j;
        __syncthreads();
    }
}

// ---------------------------------------------------------------------------
// K4: per-batch merge of CHUNKS*K candidates -> global top-K (in sorted order).
// ISDC=true: also compute A1 (argmax of per-pixel channel max, first-occurrence).
// ISDC=false: write the K selected indices for the A2 cross-batch gather.
template <bool ISDC>
__global__ __launch_bounds__(256) void merge_topk_kernel(
    const float* __restrict__ ckey, const int* __restrict__ cidx,
    const float* __restrict__ img, float* __restrict__ A1, int* __restrict__ idx2all) {
    int b = blockIdx.x;
    __shared__ float keys[NCAND];
    __shared__ int idxs[NCAND];
    __shared__ float rk[256];
    __shared__ int ri[256];
    __shared__ int rs[256];
    __shared__ int finals[K];
    for (int i = threadIdx.x; i < NCAND; i += 256) {
        keys[i] = ckey[(size_t)b * NCAND + i];
        idxs[i] = cidx[(size_t)b * NCAND + i];
    }
    __syncthreads();
    for (int r = 0; r < K; ++r) {
        float bk = -FINF;
        int bi = INT_MAX;
        int bs = -1;
        for (int i = threadIdx.x; i < NCAND; i += 256) {
            float kk = keys[i];
            if (kk > bk || (kk == bk && idxs[i] < bi)) { bk = kk; bi = idxs[i]; bs = i; }
        }
        rk[threadIdx.x] = bk;
        ri[threadIdx.x] = bi;
        rs[threadIdx.x] = bs;
        __syncthreads();
        for (int s = 128; s > 0; s >>= 1) {
            if (threadIdx.x < s) {
                float ok = rk[threadIdx.x + s];
                int oi = ri[threadIdx.x + s];
                if (ok > rk[threadIdx.x] || (ok == rk[threadIdx.x] && oi < ri[threadIdx.x])) {
                    rk[threadIdx.x] = ok;
                    ri[threadIdx.x] = oi;
                    rs[threadIdx.x] = rs[threadIdx.x + s];
                }
            }
            __syncthreads();
        }
        if (threadIdx.x == 0) {
            finals[r] = ri[0];
            keys[rs[0]] = -FINF; // mask the winner
        }
        __syncthreads();
    }
    if (ISDC) {
        if (threadIdx.x == 0) {
            float best = -FINF;
            int bj = 0;
            for (int j = 0; j < K; ++j) {
                int p = finals[j];
                float m = -FINF;
#pragma unroll
                for (int c = 0; c < NCH; ++c)
                    m = fmaxf(m, img[(((size_t)(b * NCH + c)) << 18) + p]);
                if (m > best) { best = m; bj = j; } // strict > = first occurrence
            }
            int p = finals[bj];
#pragma unroll
            for (int c = 0; c < NCH; ++c)
                A1[b * NCH + c] = img[(((size_t)(b * NCH + c)) << 18) + p];
        }
    } else {
        if (threadIdx.x < K) idx2all[b * K + threadIdx.x] = finals[threadIdx.x];
    }
}

// ---------------------------------------------------------------------------
// K5: A2 (mean over ALL batches' bottom-k indices — faithful to the reference's
// batch-mixing), A = 0.75*A1 + 0.25*A2, d = (1 - A) + 1e-6
__global__ __launch_bounds__(256) void compute_A_kernel(
    const float* __restrict__ img, const int* __restrict__ idx2all,
    const float* __restrict__ A1, float* __restrict__ dvec) {
    int b = blockIdx.x;
    __shared__ float ssum[256];
    for (int c = 0; c < NCH; ++c) {
        float s = 0.0f;
        for (int j = threadIdx.x; j < BK; j += 256)
            s += img[(((size_t)(b * NCH + c)) << 18) + idx2all[j]];
        ssum[threadIdx.x] = s;
        __syncthreads();
        for (int st = 128; st > 0; st >>= 1) {
            if (threadIdx.x < st) ssum[threadIdx.x] += ssum[threadIdx.x + st];
            __syncthreads();
        }
        if (threadIdx.x == 0) {
            float A2 = ssum[0] / (float)BK;
            float A = 0.75f * A1[b * NCH + c] + 0.25f * A2;
            dvec[b * NCH + c] = (1.0f - A) + 1e-6f;
        }
        __syncthreads();
    }
}

// ---------------------------------------------------------------------------
// K6: out = concat([x, t], ch axis); t = 1 - 0.95 * min_c (1 - Vmax_c)/d_c
__global__ __launch_bounds__(256) void final_kernel(
    const float* __restrict__ x, const float* __restrict__ vmax,
    const float* __restrict__ dvec, float* __restrict__ out) {
    int i = blockIdx.x * blockDim.x + threadIdx.x;
    if (i >= BATCH * HW) return;
    int b = i >> 18;
    int p = i & (HW - 1);
    float mn = FINF;
#pragma unroll
    for (int c = 0; c < NCH; ++c) {
        size_t src = (((size_t)(b * NCH + c)) << 18) + p;
        float xv = x[src];
        out[(((size_t)(b * 4 + c)) << 18) + p] = xv;
        float qc = (1.0f - vmax[src]) / dvec[b * NCH + c];
        mn = fminf(mn, qc);
    }
    out[(((size_t)(b * 4 + 3)) << 18) + p] = 1.0f - 0.95f * mn;
}

// ---------------------------------------------------------------------------
extern "C" void kernel_launch(void* const* d_in, const int* in_sizes, int n_in,
                              void* d_out, int out_size, void* d_ws, size_t ws_size,
                              hipStream_t stream) {
    const float* x = (const float*)d_in[0];
    float* out = (float*)d_out;

    const size_t nCh = (size_t)BATCH * NCH * HW; // 12582912
    const size_t nPix = (size_t)BATCH * HW;      // 4194304

    float* ws = (float*)d_ws;
    float* Hmax = ws;
    float* Hmin = Hmax + nCh;
    float* Vmax = Hmin + nCh;
    float* bc = Vmax + nCh;
    float* dc = bc + nPix;
    float* ckey_dc = dc + nPix;
    int* cidx_dc = (int*)(ckey_dc + (size_t)BATCH * NCAND);
    float* ckey_bc = (float*)(cidx_dc + (size_t)BATCH * NCAND);
    int* cidx_bc = (int*)(ckey_bc + (size_t)BATCH * NCAND);
    float* A1 = (float*)(cidx_bc + (size_t)BATCH * NCAND);
    int* idx2all = (int*)(A1 + BATCH * NCH);
    float* dvec = (float*)(idx2all + BK);

    hpool_kernel<<<BATCH * NCH * H, 256, 0, stream>>>(x, Hmax, Hmin);
    vpool_kernel<<<(BATCH * HW + 255) / 256, 256, 0, stream>>>(Hmax, Hmin, Vmax, bc, dc);
    chunk_topk_kernel<false><<<BATCH * CHUNKS, 256, 0, stream>>>(dc, ckey_dc, cidx_dc);
    chunk_topk_kernel<true><<<BATCH * CHUNKS, 256, 0, stream>>>(bc, ckey_bc, cidx_bc);
    merge_topk_kernel<true><<<BATCH, 256, 0, stream>>>(ckey_dc, cidx_dc, x, A1, nullptr);
    merge_topk_kernel<false><<<BATCH, 256, 0, stream>>>(ckey_bc, cidx_bc, x, nullptr, idx2all);
    compute_A_kernel<<<BATCH, 256, 0, stream>>>(x, idx2all, A1, dvec);
    final_kernel<<<(BATCH * HW + 255) / 256, 256, 0, stream>>>(x, Vmax, dvec, out);
}

// Round 2
// 146.134 us; speedup vs baseline: 3.1802x; 3.1802x over previous
//
#include <hip/hip_runtime.h>
#include <hip/hip_bf16.h>
#include <climits>

// Problem constants (fixed by setup_inputs)
#define BATCH 16
#define NCH 3
#define H 512
#define W 512
#define HW (H * W)          // 262144 = 2^18
#define PAD 7
#define WIN 15
#define K 26                // int(0.0001 * 512 * 512)
#define CHUNK 2048
#define CHUNKS (HW / CHUNK) // 128
#define NC (CHUNKS * K)     // 3328 candidates per (map,batch); 3328 = 13*256
#define BK (BATCH * K)      // 416

#define TW 64               // tile width  (outputs)
#define TH 64               // tile height (outputs)
#define IN_H 78             // TH + 14
#define INW 84              // padded LDS stride for input tile (78 cols used)
#define SHW 64              // LDS stride for h-pool result

#define FINF __builtin_inff()

template <bool MX>
__device__ __forceinline__ float op(float a, float b) { return MX ? fmaxf(a, b) : fminf(a, b); }

template <bool MX>
__device__ __forceinline__ float4 op4(float4 a, float4 b) {
    return make_float4(op<MX>(a.x, b.x), op<MX>(a.y, b.y), op<MX>(a.z, b.z), op<MX>(a.w, b.w));
}

// h-pool pass: sIn rows [0,78) cols [0,78) -> sH rows [0,78) cols [0,64)
// window of 15 starting at output col. Works on 4-col groups with a shared
// 12-wide inner max t (cols x0+3..x0+14).
template <bool MX>
__device__ __forceinline__ void pool_pass(const float (*__restrict__ sIn)[INW],
                                          float* __restrict__ sH, int u) {
    for (int it = u; it < IN_H * 16; it += 256) {
        int r = it >> 4;
        int x0 = (it & 15) << 2;
        const float* rp = &sIn[r][x0];
        float4 a = *(const float4*)(rp);
        float4 bq = *(const float4*)(rp + 4);
        float4 cq = *(const float4*)(rp + 8);
        float4 dq = *(const float4*)(rp + 12);
        float e0 = rp[16], e1 = rp[17];
        float t = op<MX>(op<MX>(op<MX>(a.w, bq.x), op<MX>(bq.y, bq.z)),
                         op<MX>(op<MX>(bq.w, cq.x), op<MX>(cq.y, cq.z)));
        t = op<MX>(t, op<MX>(op<MX>(cq.w, dq.x), op<MX>(dq.y, dq.z)));
        float o0 = op<MX>(op<MX>(a.x, a.y), op<MX>(a.z, t));
        float o1 = op<MX>(op<MX>(a.y, a.z), op<MX>(t, dq.w));
        float o2 = op<MX>(op<MX>(a.z, t), op<MX>(dq.w, e0));
        float o3 = op<MX>(op<MX>(t, dq.w), op<MX>(e0, e1));
        *(float4*)&sH[r * SHW + x0] = make_float4(o0, o1, o2, o3);
    }
}

// ---------------------------------------------------------------------------
// Fused pool kernel: per 64x64 tile, per channel: load clamped 78x78 input,
// copy x->out, h-pool(max) -> v-pool(max) -> Vmax + bc-accum, h-pool(min) ->
// v-pool(min) -> dc-accum. Clamp padding == SAME -inf/+inf padding for max/min
// (the clamped coordinate's value is itself inside every window that needs it).
__global__ __launch_bounds__(256, 3) void pool_kernel(
    const float* __restrict__ x, float* __restrict__ vmax,
    float* __restrict__ dc, float* __restrict__ bc, float* __restrict__ out) {
    __shared__ float sIn[IN_H][INW];
    __shared__ float sH[IN_H * SHW];
    int blk = blockIdx.x;
    int b = blk >> 6;
    int tile = blk & 63;
    int ty0 = (tile >> 3) << 6;
    int tx0 = (tile & 7) << 6;
    int u = threadIdx.x;
    int xo = (u & 15) << 2;   // 4-col group
    int yo = (u >> 4) << 2;   // 4-row group
    float4 bcv[4], dcv[4];
#pragma unroll
    for (int i = 0; i < 4; ++i) {
        bcv[i] = make_float4(-FINF, -FINF, -FINF, -FINF);
        dcv[i] = make_float4(FINF, FINF, FINF, FINF);
    }
    for (int c = 0; c < NCH; ++c) {
        const float* xp = x + (((size_t)(b * NCH + c)) << 18);
        for (int idx = u; idx < IN_H * 78; idx += 256) {
            int r = idx / 78;
            int cc = idx - r * 78;
            int gy = ty0 - PAD + r;
            gy = gy < 0 ? 0 : (gy > H - 1 ? H - 1 : gy);
            int gx = tx0 - PAD + cc;
            gx = gx < 0 ? 0 : (gx > W - 1 ? W - 1 : gx);
            sIn[r][cc] = xp[(gy << 9) + gx];
        }
        __syncthreads();
        // copy x -> out channel c (tile interior lives at sIn[7..70][7..70])
        float* outp = out + (((size_t)(b * 4 + c)) << 18);
#pragma unroll
        for (int i = 0; i < 4; ++i) {
            float4 vv = make_float4(sIn[7 + yo + i][7 + xo], sIn[7 + yo + i][8 + xo],
                                    sIn[7 + yo + i][9 + xo], sIn[7 + yo + i][10 + xo]);
            *(float4*)&outp[((ty0 + yo + i) << 9) + tx0 + xo] = vv;
        }
        // ---- max pass ----
        pool_pass<true>(sIn, sH, u);
        __syncthreads();
        {
            float* vp = vmax + (((size_t)(b * NCH + c)) << 18);
            float4 t4 = *(const float4*)&sH[(yo + 3) * SHW + xo];
#pragma unroll
            for (int j = 4; j <= 14; ++j)
                t4 = op4<true>(t4, *(const float4*)&sH[(yo + j) * SHW + xo]);
            float4 a0 = *(const float4*)&sH[(yo + 0) * SHW + xo];
            float4 a1 = *(const float4*)&sH[(yo + 1) * SHW + xo];
            float4 a2 = *(const float4*)&sH[(yo + 2) * SHW + xo];
            float4 b15 = *(const float4*)&sH[(yo + 15) * SHW + xo];
            float4 b16 = *(const float4*)&sH[(yo + 16) * SHW + xo];
            float4 b17 = *(const float4*)&sH[(yo + 17) * SHW + xo];
            float4 o0 = op4<true>(op4<true>(a0, a1), op4<true>(a2, t4));
            float4 o1 = op4<true>(op4<true>(a1, a2), op4<true>(t4, b15));
            float4 o2 = op4<true>(op4<true>(a2, t4), op4<true>(b15, b16));
            float4 o3 = op4<true>(op4<true>(t4, b15), op4<true>(b16, b17));
            *(float4*)&vp[((ty0 + yo + 0) << 9) + tx0 + xo] = o0;
            *(float4*)&vp[((ty0 + yo + 1) << 9) + tx0 + xo] = o1;
            *(float4*)&vp[((ty0 + yo + 2) << 9) + tx0 + xo] = o2;
            *(float4*)&vp[((ty0 + yo + 3) << 9) + tx0 + xo] = o3;
            bcv[0] = op4<true>(bcv[0], o0);
            bcv[1] = op4<true>(bcv[1], o1);
            bcv[2] = op4<true>(bcv[2], o2);
            bcv[3] = op4<true>(bcv[3], o3);
        }
        __syncthreads();
        // ---- min pass ----
        pool_pass<false>(sIn, sH, u);
        __syncthreads();
        {
            float4 t4 = *(const float4*)&sH[(yo + 3) * SHW + xo];
#pragma unroll
            for (int j = 4; j <= 14; ++j)
                t4 = op4<false>(t4, *(const float4*)&sH[(yo + j) * SHW + xo]);
            float4 a0 = *(const float4*)&sH[(yo + 0) * SHW + xo];
            float4 a1 = *(const float4*)&sH[(yo + 1) * SHW + xo];
            float4 a2 = *(const float4*)&sH[(yo + 2) * SHW + xo];
            float4 b15 = *(const float4*)&sH[(yo + 15) * SHW + xo];
            float4 b16 = *(const float4*)&sH[(yo + 16) * SHW + xo];
            float4 b17 = *(const float4*)&sH[(yo + 17) * SHW + xo];
            float4 o0 = op4<false>(op4<false>(a0, a1), op4<false>(a2, t4));
            float4 o1 = op4<false>(op4<false>(a1, a2), op4<false>(t4, b15));
            float4 o2 = op4<false>(op4<false>(a2, t4), op4<false>(b15, b16));
            float4 o3 = op4<false>(op4<false>(t4, b15), op4<false>(b16, b17));
            dcv[0] = op4<false>(dcv[0], o0);
            dcv[1] = op4<false>(dcv[1], o1);
            dcv[2] = op4<false>(dcv[2], o2);
            dcv[3] = op4<false>(dcv[3], o3);
        }
        __syncthreads();
    }
#pragma unroll
    for (int i = 0; i < 4; ++i) {
        *(float4*)&bc[((size_t)b << 18) + ((ty0 + yo + i) << 9) + tx0 + xo] = bcv[i];
        *(float4*)&dc[((size_t)b << 18) + ((ty0 + yo + i) << 9) + tx0 + xo] = dcv[i];
    }
}

// ---------------------------------------------------------------------------
// u64-packed selection key: (key<<32) | (0x7FFFFFFF - idx). Larger u64 ==
// (value desc, index asc) winner — exactly jax.lax.top_k's tie rule.
// dc map: key = float bits (non-negative floats are uint-ordered).
// bc map: key = ~bits (bottom-k == top-k of complemented bits).
__device__ __forceinline__ unsigned long long shfl_xor_u64(unsigned long long v, int m) {
    int lo = __shfl_xor((int)(unsigned)(v & 0xFFFFFFFFull), m);
    int hi = __shfl_xor((int)(unsigned)(v >> 32), m);
    return ((unsigned long long)(unsigned)hi << 32) | (unsigned)lo;
}

// Wave-per-chunk exact top-K. No barriers: each 64-lane wave owns one
// (map, batch, chunk) of 2048 elements, 32 per lane.
__global__ __launch_bounds__(256) void chunk_topk_kernel(
    const float* __restrict__ dc, const float* __restrict__ bc,
    unsigned* __restrict__ ckey, int* __restrict__ cidx) {
    int wg = blockIdx.x * 4 + (threadIdx.x >> 6); // 0..4095
    int lane = threadIdx.x & 63;
    int map = wg >> 11;
    int rest = wg & 2047;
    int b = rest >> 7;
    int ch = rest & 127;
    const float* mp = (map ? bc : dc) + ((size_t)b << 18) + (size_t)ch * CHUNK;
    unsigned long long kk[32];
#pragma unroll
    for (int j = 0; j < 32; ++j) {
        unsigned bits = __float_as_uint(mp[j * 64 + lane]);
        unsigned k = map ? ~bits : bits;
        int g = ch * CHUNK + j * 64 + lane;
        kk[j] = ((unsigned long long)k << 32) | (unsigned)(0x7FFFFFFF - g);
    }
    unsigned* okey = ckey + ((size_t)(map * BATCH + b)) * NC + ch * K;
    int* oidx = cidx + ((size_t)(map * BATCH + b)) * NC + ch * K;
    for (int r = 0; r < K; ++r) {
        // 4 independent chains to cut the dep-chain depth
        unsigned long long b0 = kk[0], b1 = kk[1], b2 = kk[2], b3 = kk[3];
#pragma unroll
        for (int j = 4; j < 32; j += 4) {
            b0 = kk[j] > b0 ? kk[j] : b0;
            b1 = kk[j + 1] > b1 ? kk[j + 1] : b1;
            b2 = kk[j + 2] > b2 ? kk[j + 2] : b2;
            b3 = kk[j + 3] > b3 ? kk[j + 3] : b3;
        }
        b0 = b1 > b0 ? b1 : b0;
        b2 = b3 > b2 ? b3 : b2;
        unsigned long long best = b2 > b0 ? b2 : b0;
#pragma unroll
        for (int s = 1; s < 64; s <<= 1) {
            unsigned long long ob = shfl_xor_u64(best, s);
            best = ob > best ? ob : best;
        }
        if (lane == 0) {
            okey[r] = (unsigned)(best >> 32);
            oidx[r] = 0x7FFFFFFF - (int)(unsigned)(best & 0xFFFFFFFFull);
        }
#pragma unroll
        for (int j = 0; j < 32; ++j)
            kk[j] = (kk[j] == best) ? 0ull : kk[j];
    }
}

// ---------------------------------------------------------------------------
// Per-(map,batch) merge of 3328 candidates -> global top-K in sorted order.
// Candidates live in registers (13 u64/thread); 2 syncs per round.
// map 0 (dc): compute A1. map 1 (bc): write the K indices for A2.
__global__ __launch_bounds__(256) void merge_topk_kernel(
    const unsigned* __restrict__ ckey, const int* __restrict__ cidx,
    const float* __restrict__ img, float* __restrict__ A1, int* __restrict__ idx2all) {
    int blk = blockIdx.x;
    int map = blk >> 4;
    int b = blk & 15;
    int t = threadIdx.x;
    int lane = t & 63, wv = t >> 6;
    const unsigned* kp = ckey + ((size_t)(map * BATCH + b)) * NC;
    const int* ip = cidx + ((size_t)(map * BATCH + b)) * NC;
    unsigned long long kk[13];
#pragma unroll
    for (int q = 0; q < 13; ++q) {
        unsigned k = kp[q * 256 + t];
        int g = ip[q * 256 + t];
        kk[q] = ((unsigned long long)k << 32) | (unsigned)(0x7FFFFFFF - g);
    }
    __shared__ unsigned long long sB[4];
    __shared__ int sS[4];
    __shared__ int sFin[K];
    __shared__ float sM[K];
    for (int r = 0; r < K; ++r) {
        unsigned long long best = 0;
        int slot = -1;
#pragma unroll
        for (int q = 0; q < 13; ++q)
            if (kk[q] > best) { best = kk[q]; slot = q * 256 + t; }
#pragma unroll
        for (int s = 1; s < 64; s <<= 1) {
            unsigned long long ob = shfl_xor_u64(best, s);
            int os = __shfl_xor(slot, s);
            if (ob > best) { best = ob; slot = os; }
        }
        if (lane == 0) { sB[wv] = best; sS[wv] = slot; }
        __syncthreads();
        unsigned long long wb = sB[0];
        int ws = sS[0];
        if (sB[1] > wb) { wb = sB[1]; ws = sS[1]; }
        if (sB[2] > wb) { wb = sB[2]; ws = sS[2]; }
        if (sB[3] > wb) { wb = sB[3]; ws = sS[3]; }
        int g = 0x7FFFFFFF - (int)(unsigned)(wb & 0xFFFFFFFFull);
        if (t == 0) {
            if (map == 0) sFin[r] = g;
            else idx2all[b * K + r] = g;
        }
        if ((ws & 255) == t) {
            int qq = ws >> 8;
#pragma unroll
            for (int q = 0; q < 13; ++q)
                if (q == qq) kk[q] = 0ull;
        }
        __syncthreads();
    }
    if (map == 0) {
        if (t < K) {
            int p = sFin[t];
            float m = img[(((size_t)(b * NCH + 0)) << 18) + p];
            m = fmaxf(m, img[(((size_t)(b * NCH + 1)) << 18) + p]);
            m = fmaxf(m, img[(((size_t)(b * NCH + 2)) << 18) + p]);
            sM[t] = m;
        }
        __syncthreads();
        if (t == 0) {
            float bm = -FINF;
            int bj = 0;
            for (int j = 0; j < K; ++j)
                if (sM[j] > bm) { bm = sM[j]; bj = j; } // strict > = first occurrence
            int p = sFin[bj];
#pragma unroll
            for (int c = 0; c < NCH; ++c)
                A1[b * NCH + c] = img[(((size_t)(b * NCH + c)) << 18) + p];
        }
    }
}

// ---------------------------------------------------------------------------
// A2 (mean over ALL batches' bottom-k indices — faithful to the reference's
// batch-mixing bug), A = 0.75*A1 + 0.25*A2, d = (1 - A) + 1e-6
__global__ __launch_bounds__(256) void compute_A_kernel(
    const float* __restrict__ img, const int* __restrict__ idx2all,
    const float* __restrict__ A1, float* __restrict__ dvec) {
    int b = blockIdx.x;
    __shared__ float ssum[256];
    for (int c = 0; c < NCH; ++c) {
        float s = 0.0f;
        for (int j = threadIdx.x; j < BK; j += 256)
            s += img[(((size_t)(b * NCH + c)) << 18) + idx2all[j]];
        ssum[threadIdx.x] = s;
        __syncthreads();
        for (int st = 128; st > 0; st >>= 1) {
            if (threadIdx.x < st) ssum[threadIdx.x] += ssum[threadIdx.x + st];
            __syncthreads();
        }
        if (threadIdx.x == 0) {
            float A2 = ssum[0] / (float)BK;
            float A = 0.75f * A1[b * NCH + c] + 0.25f * A2;
            dvec[b * NCH + c] = (1.0f - A) + 1e-6f;
        }
        __syncthreads();
    }
}

// ---------------------------------------------------------------------------
// t = 1 - 0.95 * min_c (1 - Vmax_c)/d_c   (x-channels already written by pool)
__global__ __launch_bounds__(256) void final_t_kernel(
    const float* __restrict__ vmax, const float* __restrict__ dvec,
    float* __restrict__ out) {
    int i4 = (blockIdx.x * 256 + threadIdx.x) << 2;
    int b = i4 >> 18;
    int p = i4 & (HW - 1);
    const float* vp = vmax + (((size_t)(b * NCH)) << 18) + p;
    float r0 = 1.0f / dvec[b * NCH + 0];
    float r1 = 1.0f / dvec[b * NCH + 1];
    float r2 = 1.0f / dvec[b * NCH + 2];
    float4 v0 = *(const float4*)(vp);
    float4 v1 = *(const float4*)(vp + ((size_t)1 << 18));
    float4 v2 = *(const float4*)(vp + ((size_t)2 << 18));
    float4 t;
    t.x = 1.0f - 0.95f * fminf(fminf((1.0f - v0.x) * r0, (1.0f - v1.x) * r1), (1.0f - v2.x) * r2);
    t.y = 1.0f - 0.95f * fminf(fminf((1.0f - v0.y) * r0, (1.0f - v1.y) * r1), (1.0f - v2.y) * r2);
    t.z = 1.0f - 0.95f * fminf(fminf((1.0f - v0.z) * r0, (1.0f - v1.z) * r1), (1.0f - v2.z) * r2);
    t.w = 1.0f - 0.95f * fminf(fminf((1.0f - v0.w) * r0, (1.0f - v1.w) * r1), (1.0f - v2.w) * r2);
    *(float4*)&out[(((size_t)(b * 4 + 3)) << 18) + p] = t;
}

// ---------------------------------------------------------------------------
extern "C" void kernel_launch(void* const* d_in, const int* in_sizes, int n_in,
                              void* d_out, int out_size, void* d_ws, size_t ws_size,
                              hipStream_t stream) {
    const float* x = (const float*)d_in[0];
    float* out = (float*)d_out;

    const size_t nCh = (size_t)BATCH * NCH * HW; // 12582912
    const size_t nPix = (size_t)BATCH * HW;      // 4194304

    float* ws = (float*)d_ws;
    float* Vmax = ws;
    float* dc = Vmax + nCh;
    float* bc = dc + nPix;
    unsigned* ckey = (unsigned*)(bc + nPix);
    int* cidx = (int*)(ckey + (size_t)2 * BATCH * NC);
    float* A1 = (float*)(cidx + (size_t)2 * BATCH * NC);
    int* idx2all = (int*)(A1 + BATCH * NCH);
    float* dvec = (float*)(idx2all + BK);

    pool_kernel<<<BATCH * 64, 256, 0, stream>>>(x, Vmax, dc, bc, out);
    chunk_topk_kernel<<<1024, 256, 0, stream>>>(dc, bc, ckey, cidx);
    merge_topk_kernel<<<32, 256, 0, stream>>>(ckey, cidx, x, A1, idx2all);
    compute_A_kernel<<<BATCH, 256, 0, stream>>>(x, idx2all, A1, dvec);
    final_t_kernel<<<(int)(nPix / 4 / 256), 256, 0, stream>>>(Vmax, dvec, out);
}

// Round 3
// 120.270 us; speedup vs baseline: 3.8641x; 1.2150x over previous
//
#include <hip/hip_runtime.h>
#include <hip/hip_bf16.h>

// Problem constants (fixed by setup_inputs)
#define BATCH 16
#define NCH 3
#define H 512
#define W 512
#define HW (H * W)          // 262144 = 2^18
#define PAD 7
#define K 26                // int(0.0001 * 512 * 512)
#define NSUB 1024           // sub-chunks (4 rows x 64 cols = 256 px) per batch
#define NPAIR 32            // 2 maps x 16 batches
#define CAND_STRIDE (NSUB * K)
#define BK (BATCH * K)      // 416

#define TW 64               // pool tile width (outputs)
#define TH 32               // pool tile height (outputs)
#define IN_ROWS 46          // TH + 14
#define IN_COLS 78          // TW + 14
#define INW 84              // LDS stride for input tile
#define SHW 64              // LDS stride for h-pool result

#define FINF __builtin_inff()

// monotone float->u32 key (order-preserving for all floats)
__device__ __forceinline__ unsigned mkey(float f) {
    unsigned u = __float_as_uint(f);
    unsigned m = (unsigned)(((int)u) >> 31) | 0x80000000u;
    return u ^ m;
}

__device__ __forceinline__ unsigned long long shfl_xor_u64(unsigned long long v, int m) {
    int lo = __shfl_xor((int)(unsigned)(v & 0xFFFFFFFFull), m);
    int hi = __shfl_xor((int)(unsigned)(v >> 32), m);
    return ((unsigned long long)(unsigned)hi << 32) | (unsigned)lo;
}

template <bool MX>
__device__ __forceinline__ float op(float a, float b) { return MX ? fmaxf(a, b) : fminf(a, b); }
template <bool MX>
__device__ __forceinline__ float4 op4(float4 a, float4 b) {
    return make_float4(op<MX>(a.x, b.x), op<MX>(a.y, b.y), op<MX>(a.z, b.z), op<MX>(a.w, b.w));
}

// v-pool of one map half: 18 LDS rows -> 4 output rows (+ optional global write)
template <bool MX, bool WR>
__device__ __forceinline__ void vpool_half(const float* __restrict__ sH, int vy, int vx,
                                           float4 acc[4], float* __restrict__ vp, int gbase) {
    const float* p0 = sH + vy * SHW + vx;
    float4 t4 = *(const float4*)(p0 + 3 * SHW);
#pragma unroll
    for (int j = 4; j <= 14; ++j) t4 = op4<MX>(t4, *(const float4*)(p0 + j * SHW));
    float4 a0 = *(const float4*)(p0);
    float4 a1 = *(const float4*)(p0 + SHW);
    float4 a2 = *(const float4*)(p0 + 2 * SHW);
    float4 b15 = *(const float4*)(p0 + 15 * SHW);
    float4 b16 = *(const float4*)(p0 + 16 * SHW);
    float4 b17 = *(const float4*)(p0 + 17 * SHW);
    float4 o0 = op4<MX>(op4<MX>(a0, a1), op4<MX>(a2, t4));
    float4 o1 = op4<MX>(op4<MX>(a1, a2), op4<MX>(t4, b15));
    float4 o2 = op4<MX>(op4<MX>(a2, t4), op4<MX>(b15, b16));
    float4 o3 = op4<MX>(op4<MX>(t4, b15), op4<MX>(b16, b17));
    if (WR) {
        *(float4*)&vp[gbase] = o0;
        *(float4*)&vp[gbase + 512] = o1;
        *(float4*)&vp[gbase + 1024] = o2;
        *(float4*)&vp[gbase + 1536] = o3;
    }
    acc[0] = op4<MX>(acc[0], o0);
    acc[1] = op4<MX>(acc[1], o1);
    acc[2] = op4<MX>(acc[2], o2);
    acc[3] = op4<MX>(acc[3], o3);
}

// ---------------------------------------------------------------------------
// Fused pool: per 64x32 tile, per channel: stage clamped 78x46 input (+ x->out
// copy), ONE h-pool pass computing max+min from the same registers, v-pool
// split by thread halves (u<128: max map -> Vmax + bc keys; u>=128: min map ->
// dc keys). Also emits per-sub-chunk (4x64 px) key maxima for screening.
__global__ __launch_bounds__(256, 4) void pool_kernel(
    const float* __restrict__ x, float* __restrict__ vmax,
    unsigned* __restrict__ dcK, unsigned* __restrict__ bcK,
    unsigned* __restrict__ subkey, float* __restrict__ out) {
    __shared__ __align__(16) float sIn[IN_ROWS][INW];
    __shared__ __align__(16) float sHmax[IN_ROWS * SHW];
    __shared__ __align__(16) float sHmin[IN_ROWS * SHW];
    int blk = blockIdx.x;
    int b = blk >> 7;
    int tile = blk & 127;
    int tx0 = (tile & 7) << 6;
    int ty0 = (tile >> 3) << 5;
    int u = threadIdx.x;
    int half = u >> 7;      // 0: max map, 1: min map
    int v = u & 127;
    int rg = v >> 4;        // 0..7  (sub-chunk row group)
    int cg = v & 15;
    int vx = cg << 2;
    int vy = rg << 2;
    float4 acc[4];
    float ainit = half ? FINF : -FINF;
#pragma unroll
    for (int i = 0; i < 4; ++i) acc[i] = make_float4(ainit, ainit, ainit, ainit);

    for (int c = 0; c < NCH; ++c) {
        const float* xp = x + (((size_t)(b * NCH + c)) << 18);
        float* outp = out + (((size_t)(b * 4 + c)) << 18);
        // ---- stage (+ x->out copy) ----
        {
            int r = u / IN_COLS;
            int cc = u - r * IN_COLS;
            for (int idx = u; idx < IN_ROWS * IN_COLS; idx += 256) {
                int gy = ty0 - PAD + r;
                gy = gy < 0 ? 0 : (gy > H - 1 ? H - 1 : gy);
                int gx = tx0 - PAD + cc;
                gx = gx < 0 ? 0 : (gx > W - 1 ? W - 1 : gx);
                float vv = xp[(gy << 9) + gx];
                sIn[r][cc] = vv;
                if (r >= PAD && r < PAD + TH && cc >= PAD && cc < PAD + TW)
                    outp[((ty0 + r - PAD) << 9) + tx0 + cc - PAD] = vv;
                cc += 22; r += 3;                       // += 256 over 78-col rows
                if (cc >= IN_COLS) { cc -= IN_COLS; r += 1; }
            }
        }
        __syncthreads();
        // ---- single h-pool pass: max AND min from the same registers ----
        for (int it = u; it < IN_ROWS * 16; it += 256) {
            int r = it >> 4;
            int x0 = (it & 15) << 2;
            const float* rp = &sIn[r][x0];
            float4 a = *(const float4*)(rp);
            float4 bq = *(const float4*)(rp + 4);
            float4 cq = *(const float4*)(rp + 8);
            float4 dq = *(const float4*)(rp + 12);
            float e0 = rp[16], e1 = rp[17];
            float tmx = fmaxf(fmaxf(fmaxf(fmaxf(a.w, bq.x), fmaxf(bq.y, bq.z)),
                                    fmaxf(fmaxf(bq.w, cq.x), fmaxf(cq.y, cq.z))),
                              fmaxf(fmaxf(cq.w, dq.x), fmaxf(dq.y, dq.z)));
            float tmn = fminf(fminf(fminf(fminf(a.w, bq.x), fminf(bq.y, bq.z)),
                                    fminf(fminf(bq.w, cq.x), fminf(cq.y, cq.z))),
                              fminf(fminf(cq.w, dq.x), fminf(dq.y, dq.z)));
            *(float4*)&sHmax[r * SHW + x0] = make_float4(
                fmaxf(fmaxf(a.x, a.y), fmaxf(a.z, tmx)),
                fmaxf(fmaxf(a.y, a.z), fmaxf(tmx, dq.w)),
                fmaxf(fmaxf(a.z, tmx), fmaxf(dq.w, e0)),
                fmaxf(fmaxf(tmx, dq.w), fmaxf(e0, e1)));
            *(float4*)&sHmin[r * SHW + x0] = make_float4(
                fminf(fminf(a.x, a.y), fminf(a.z, tmn)),
                fminf(fminf(a.y, a.z), fminf(tmn, dq.w)),
                fminf(fminf(a.z, tmn), fminf(dq.w, e0)),
                fminf(fminf(tmn, dq.w), fminf(e0, e1)));
        }
        __syncthreads();
        // ---- v-pool, half-split ----
        int gbase = ((ty0 + vy) << 9) + tx0 + vx;
        if (half == 0) {
            float* vp = vmax + (((size_t)(b * NCH + c)) << 18);
            vpool_half<true, true>(sHmax, vy, vx, acc, vp, gbase);
        } else {
            vpool_half<false, false>(sHmin, vy, vx, acc, nullptr, 0);
        }
        __syncthreads();
    }
    // ---- per-pixel key maps + per-sub-chunk key maxima ----
    unsigned gb = ((unsigned)b << 18) + ((ty0 + vy) << 9) + tx0 + vx;
    if (half == 0) {
        float mn = FINF;
#pragma unroll
        for (int i = 0; i < 4; ++i) {
            float4 o = acc[i];
            *(uint4*)&bcK[gb + (i << 9)] =
                make_uint4(~mkey(o.x), ~mkey(o.y), ~mkey(o.z), ~mkey(o.w));
            mn = fminf(mn, fminf(fminf(o.x, o.y), fminf(o.z, o.w)));
        }
#pragma unroll
        for (int s = 1; s < 16; s <<= 1) mn = fminf(mn, __shfl_xor(mn, s));
        if (cg == 0) subkey[(BATCH + b) * NSUB + tile * 8 + rg] = ~mkey(mn);
    } else {
        float mx = -FINF;
#pragma unroll
        for (int i = 0; i < 4; ++i) {
            float4 o = acc[i];
            *(uint4*)&dcK[gb + (i << 9)] =
                make_uint4(mkey(o.x), mkey(o.y), mkey(o.z), mkey(o.w));
            mx = fmaxf(mx, fmaxf(fmaxf(o.x, o.y), fmaxf(o.z, o.w)));
        }
#pragma unroll
        for (int s = 1; s < 16; s <<= 1) mx = fmaxf(mx, __shfl_xor(mx, s));
        if (cg == 0) subkey[b * NSUB + tile * 8 + rg] = mkey(mx);
    }
}

// ---------------------------------------------------------------------------
// Screen + extract. 8 blocks per (map,batch) pair. Wave 0 of each block
// (redundantly, deterministically) computes tau = 26th-largest chunk key-max
// (chunk = 2048 px = 8 subs). Theorem: any global-top-26 element's sub-chunk
// has key-max >= tau. Qualifying subs (~26-40 of 1024) get exact 26-round
// (value,idx)-packed extraction, one wave per sub.
__global__ __launch_bounds__(256) void select_kernel(
    const unsigned* __restrict__ dcK, const unsigned* __restrict__ bcK,
    const unsigned* __restrict__ subkey, unsigned long long* __restrict__ cand,
    int* __restrict__ nQ) {
    int blk = blockIdx.x;       // 256 blocks
    int pair = blk >> 3;
    int bslot = blk & 7;
    int map = pair >> 4;
    int b = pair & 15;
    int t = threadIdx.x;
    int wv = t >> 6, lane = t & 63;
    __shared__ int sList[NSUB];
    __shared__ int sN;
    if (wv == 0) {
        const unsigned* sk = subkey + (size_t)pair * NSUB + lane * 16;
        unsigned k[16];
        *(uint4*)&k[0] = *(const uint4*)&sk[0];
        *(uint4*)&k[4] = *(const uint4*)&sk[4];
        *(uint4*)&k[8] = *(const uint4*)&sk[8];
        *(uint4*)&k[12] = *(const uint4*)&sk[12];
        unsigned c0 = k[0], c1 = k[8];
#pragma unroll
        for (int j = 1; j < 8; ++j) { c0 = max(c0, k[j]); c1 = max(c1, k[8 + j]); }
        unsigned long long q0 = ((unsigned long long)c0 << 32) | (unsigned)(lane * 2);
        unsigned long long q1 = ((unsigned long long)c1 << 32) | (unsigned)(lane * 2 + 1);
        unsigned tau = 0;
        for (int r = 0; r < K; ++r) {
            unsigned long long m = q0 > q1 ? q0 : q1;
#pragma unroll
            for (int s = 1; s < 64; s <<= 1) {
                unsigned long long o = shfl_xor_u64(m, s);
                m = o > m ? o : m;
            }
            if (r == K - 1) tau = (unsigned)(m >> 32);
            if (q0 == m) q0 = 0;
            if (q1 == m) q1 = 0;
        }
        int base = 0;
        for (int j = 0; j < 16; ++j) {
            bool q = k[j] >= tau;
            unsigned long long mk = __ballot(q);
            if (q) sList[base + __popcll(mk & ((1ull << lane) - 1ull))] = lane * 16 + j;
            base += (int)__popcll(mk);
        }
        if (lane == 0) {
            sN = base;
            if (bslot == 0) nQ[pair] = base;
        }
    }
    __syncthreads();
    int n = sN;
    const unsigned* mapK = (map ? bcK : dcK) + ((size_t)b << 18);
    for (int s_i = bslot * 4 + wv; s_i < n; s_i += 32) {
        int sub = sList[s_i];
        int stile = sub >> 3, srg = sub & 7;
        int tx0 = (stile & 7) << 6;
        int ys = ((stile >> 3) << 5) + srg * 4;
        unsigned long long kk[4];
#pragma unroll
        for (int j = 0; j < 4; ++j) {
            int p = ((ys + j) << 9) + tx0 + lane;
            kk[j] = ((unsigned long long)mapK[p] << 32) | (unsigned)(0x7FFFFFFF - p);
        }
        unsigned long long* cp = cand + (size_t)pair * CAND_STRIDE + s_i * K;
        for (int r = 0; r < K; ++r) {
            unsigned long long m01 = kk[0] > kk[1] ? kk[0] : kk[1];
            unsigned long long m23 = kk[2] > kk[3] ? kk[2] : kk[3];
            unsigned long long m = m01 > m23 ? m01 : m23;
#pragma unroll
            for (int s = 1; s < 64; s <<= 1) {
                unsigned long long o = shfl_xor_u64(m, s);
                m = o > m ? o : m;
            }
            if (lane == 0) cp[r] = m;
#pragma unroll
            for (int j = 0; j < 4; ++j)
                if (kk[j] == m) kk[j] = 0;
        }
    }
}

// ---------------------------------------------------------------------------
// Per-(map,batch) merge of n*26 candidates -> global top-26 (sorted order).
// map0 (dc): A1 (argmax of per-pixel channel max, first occurrence).
// map1 (bc): the 26 indices for A2.
__global__ __launch_bounds__(256) void merge_kernel(
    const unsigned long long* __restrict__ cand, const int* __restrict__ nQ,
    const float* __restrict__ img, float* __restrict__ A1, int* __restrict__ idx2all) {
    int pair = blockIdx.x;
    int map = pair >> 4, b = pair & 15;
    int t = threadIdx.x;
    int wv = t >> 6, lane = t & 63;
    int C = nQ[pair] * K;
    const unsigned long long* cp = cand + (size_t)pair * CAND_STRIDE;
    __shared__ unsigned long long sB[4];
    __shared__ unsigned long long sWin[K];
    __shared__ unsigned long long sCarry[K];
    __shared__ float sM[K];
    int ntile = (C + 1663) / 1664;
    for (int tile = 0; tile < ntile; ++tile) {
        int lo = tile * 1664;
        int hi = C < lo + 1664 ? C : lo + 1664;
        unsigned long long kk[7], kc;
#pragma unroll
        for (int q = 0; q < 7; ++q) {
            int idx = lo + q * 256 + t;
            kk[q] = (idx < hi) ? cp[idx] : 0ull;
        }
        kc = (tile > 0 && t < K) ? sCarry[t] : 0ull;
        __syncthreads();
        for (int r = 0; r < K; ++r) {
            unsigned long long m = kc;
#pragma unroll
            for (int q = 0; q < 7; ++q)
                if (kk[q] > m) m = kk[q];
#pragma unroll
            for (int s = 1; s < 64; s <<= 1) {
                unsigned long long o = shfl_xor_u64(m, s);
                m = o > m ? o : m;
            }
            if (lane == 0) sB[wv] = m;
            __syncthreads();
            unsigned long long wb = sB[0];
            if (sB[1] > wb) wb = sB[1];
            if (sB[2] > wb) wb = sB[2];
            if (sB[3] > wb) wb = sB[3];
            if (t == 0) sWin[r] = wb;
#pragma unroll
            for (int q = 0; q < 7; ++q)
                if (kk[q] == wb) kk[q] = 0;
            if (kc == wb) kc = 0;
            __syncthreads();
        }
        if (tile + 1 < ntile) {
            if (t < K) sCarry[t] = sWin[t];
            __syncthreads();
        }
    }
    if (map == 0) {
        if (t < K) {
            int p = 0x7FFFFFFF - (int)(unsigned)(sWin[t] & 0xFFFFFFFFull);
            float m = img[(((size_t)(b * NCH + 0)) << 18) + p];
            m = fmaxf(m, img[(((size_t)(b * NCH + 1)) << 18) + p]);
            m = fmaxf(m, img[(((size_t)(b * NCH + 2)) << 18) + p]);
            sM[t] = m;
        }
        __syncthreads();
        if (t == 0) {
            float bm = -FINF;
            int bj = 0;
            for (int j = 0; j < K; ++j)
                if (sM[j] > bm) { bm = sM[j]; bj = j; }   // strict > = first occurrence
            int p = 0x7FFFFFFF - (int)(unsigned)(sWin[bj] & 0xFFFFFFFFull);
#pragma unroll
            for (int c = 0; c < NCH; ++c)
                A1[b * NCH + c] = img[(((size_t)(b * NCH + c)) << 18) + p];
        }
    } else {
        if (t < K)
            idx2all[b * K + t] = 0x7FFFFFFF - (int)(unsigned)(sWin[t] & 0xFFFFFFFFull);
    }
}

// ---------------------------------------------------------------------------
// A2 (mean over ALL batches' bottom-k indices — faithful to the reference's
// batch-mixing bug), A = 0.75*A1 + 0.25*A2, d = (1 - A) + 1e-6
__global__ __launch_bounds__(256) void compute_A_kernel(
    const float* __restrict__ img, const int* __restrict__ idx2all,
    const float* __restrict__ A1, float* __restrict__ dvec) {
    int b = blockIdx.x;
    __shared__ float ssum[256];
    for (int c = 0; c < NCH; ++c) {
        float s = 0.0f;
        for (int j = threadIdx.x; j < BK; j += 256)
            s += img[(((size_t)(b * NCH + c)) << 18) + idx2all[j]];
        ssum[threadIdx.x] = s;
        __syncthreads();
        for (int st = 128; st > 0; st >>= 1) {
            if (threadIdx.x < st) ssum[threadIdx.x] += ssum[threadIdx.x + st];
            __syncthreads();
        }
        if (threadIdx.x == 0) {
            float A2 = ssum[0] / (float)BK;
            float A = 0.75f * A1[b * NCH + c] + 0.25f * A2;
            dvec[b * NCH + c] = (1.0f - A) + 1e-6f;
        }
        __syncthreads();
    }
}

// ---------------------------------------------------------------------------
// t = 1 - 0.95 * min_c (1 - Vmax_c)/d_c   (x-channels already written by pool)
__global__ __launch_bounds__(256) void final_t_kernel(
    const float* __restrict__ vmax, const float* __restrict__ dvec,
    float* __restrict__ out) {
    int i4 = (blockIdx.x * 256 + threadIdx.x) << 2;
    int b = i4 >> 18;
    int p = i4 & (HW - 1);
    const float* vp = vmax + (((size_t)(b * NCH)) << 18) + p;
    float r0 = 1.0f / dvec[b * NCH + 0];
    float r1 = 1.0f / dvec[b * NCH + 1];
    float r2 = 1.0f / dvec[b * NCH + 2];
    float4 v0 = *(const float4*)(vp);
    float4 v1 = *(const float4*)(vp + ((size_t)1 << 18));
    float4 v2 = *(const float4*)(vp + ((size_t)2 << 18));
    float4 t;
    t.x = 1.0f - 0.95f * fminf(fminf((1.0f - v0.x) * r0, (1.0f - v1.x) * r1), (1.0f - v2.x) * r2);
    t.y = 1.0f - 0.95f * fminf(fminf((1.0f - v0.y) * r0, (1.0f - v1.y) * r1), (1.0f - v2.y) * r2);
    t.z = 1.0f - 0.95f * fminf(fminf((1.0f - v0.z) * r0, (1.0f - v1.z) * r1), (1.0f - v2.z) * r2);
    t.w = 1.0f - 0.95f * fminf(fminf((1.0f - v0.w) * r0, (1.0f - v1.w) * r1), (1.0f - v2.w) * r2);
    *(float4*)&out[(((size_t)(b * 4 + 3)) << 18) + p] = t;
}

// ---------------------------------------------------------------------------
extern "C" void kernel_launch(void* const* d_in, const int* in_sizes, int n_in,
                              void* d_out, int out_size, void* d_ws, size_t ws_size,
                              hipStream_t stream) {
    const float* x = (const float*)d_in[0];
    float* out = (float*)d_out;

    const size_t nCh = (size_t)BATCH * NCH * HW; // 12,582,912
    const size_t nPix = (size_t)BATCH * HW;      //  4,194,304

    float* ws = (float*)d_ws;
    float* Vmax = ws;
    unsigned* dcK = (unsigned*)(Vmax + nCh);
    unsigned* bcK = dcK + nPix;
    unsigned* subkey = bcK + nPix;                       // [2][16][1024]
    unsigned long long* cand =
        (unsigned long long*)(subkey + (size_t)2 * BATCH * NSUB);
    int* nQ = (int*)(cand + (size_t)NPAIR * CAND_STRIDE);
    float* A1 = (float*)(nQ + NPAIR);
    int* idx2all = (int*)(A1 + BATCH * NCH);
    float* dvec = (float*)(idx2all + BK);

    pool_kernel<<<BATCH * 128, 256, 0, stream>>>(x, Vmax, dcK, bcK, subkey, out);
    select_kernel<<<NPAIR * 8, 256, 0, stream>>>(dcK, bcK, subkey, cand, nQ);
    merge_kernel<<<NPAIR, 256, 0, stream>>>(cand, nQ, x, A1, idx2all);
    compute_A_kernel<<<BATCH, 256, 0, stream>>>(x, idx2all, A1, dvec);
    final_t_kernel<<<(int)(nPix / 4 / 256), 256, 0, stream>>>(Vmax, dvec, out);
}

// Round 4
// 108.080 us; speedup vs baseline: 4.2999x; 1.1128x over previous
//
#include <hip/hip_runtime.h>
#include <hip/hip_bf16.h>

// Problem constants (fixed by setup_inputs)
#define BATCH 16
#define NCH 3
#define H 512
#define W 512
#define HW (H * W)          // 262144 = 2^18
#define PAD 7
#define K 26                // int(0.0001 * 512 * 512)
#define NSUB 1024           // sub-chunks (4 rows x 64 cols = 256 px) per batch
#define NPAIR 32            // 2 maps x 16 batches
#define CAND_STRIDE (NSUB * K)
#define BK (BATCH * K)      // 416

#define TW 64               // pool tile width (outputs)
#define TH 32               // pool tile height (outputs)
#define IN_ROWS 46          // TH + 14
#define SHP 68              // padded LDS stride for h-pool result (64 used)

#define FINF __builtin_inff()

// monotone float->u32 key (order-preserving for all floats)
__device__ __forceinline__ unsigned mkey(float f) {
    unsigned u = __float_as_uint(f);
    unsigned m = (unsigned)(((int)u) >> 31) | 0x80000000u;
    return u ^ m;
}

__device__ __forceinline__ unsigned long long shfl_xor_u64(unsigned long long v, int m) {
    int lo = __shfl_xor((int)(unsigned)(v & 0xFFFFFFFFull), m);
    int hi = __shfl_xor((int)(unsigned)(v >> 32), m);
    return ((unsigned long long)(unsigned)hi << 32) | (unsigned)lo;
}

template <bool MX>
__device__ __forceinline__ float op(float a, float b) { return MX ? fmaxf(a, b) : fminf(a, b); }
template <bool MX>
__device__ __forceinline__ float4 op4(float4 a, float4 b) {
    return make_float4(op<MX>(a.x, b.x), op<MX>(a.y, b.y), op<MX>(a.z, b.z), op<MX>(a.w, b.w));
}

// v-pool of one map half: 18 LDS rows -> 4 output rows (+ optional global write)
template <bool MX, bool WR>
__device__ __forceinline__ void vpool_half(const float* __restrict__ sH, int vy, int vx,
                                           float4 acc[4], float* __restrict__ vp, int gbase) {
    const float* p0 = sH + vy * SHP + vx;
    float4 t4 = *(const float4*)(p0 + 3 * SHP);
#pragma unroll
    for (int j = 4; j <= 14; ++j) t4 = op4<MX>(t4, *(const float4*)(p0 + j * SHP));
    float4 a0 = *(const float4*)(p0);
    float4 a1 = *(const float4*)(p0 + SHP);
    float4 a2 = *(const float4*)(p0 + 2 * SHP);
    float4 b15 = *(const float4*)(p0 + 15 * SHP);
    float4 b16 = *(const float4*)(p0 + 16 * SHP);
    float4 b17 = *(const float4*)(p0 + 17 * SHP);
    float4 o0 = op4<MX>(op4<MX>(a0, a1), op4<MX>(a2, t4));
    float4 o1 = op4<MX>(op4<MX>(a1, a2), op4<MX>(t4, b15));
    float4 o2 = op4<MX>(op4<MX>(a2, t4), op4<MX>(b15, b16));
    float4 o3 = op4<MX>(op4<MX>(t4, b15), op4<MX>(b16, b17));
    if (WR) {
        *(float4*)&vp[gbase] = o0;
        *(float4*)&vp[gbase + 512] = o1;
        *(float4*)&vp[gbase + 1024] = o2;
        *(float4*)&vp[gbase + 1536] = o3;
    }
    acc[0] = op4<MX>(acc[0], o0);
    acc[1] = op4<MX>(acc[1], o1);
    acc[2] = op4<MX>(acc[2], o2);
    acc[3] = op4<MX>(acc[3], o3);
}

// ---------------------------------------------------------------------------
// Fused pool, no input staging: h-pool reads x straight from global (x is
// 50 MB -> L3-resident) with 5 clamped-base float4 loads per 4-output group.
// Clamping each float4 base into [0,508] reproduces clamp-to-edge padding
// EXACTLY (duplicated cols are always inside the clamped window; verified for
// all edge cases, both max and min). x->out copy rides on the center float4.
// v-pool split by thread halves (u<128: max map -> Vmax + bc; u>=128: min map
// -> dc). Emits per-sub-chunk (4x64 px) key maxima for screening.
__global__ __launch_bounds__(256, 6) void pool_kernel(
    const float* __restrict__ x, float* __restrict__ vmax,
    unsigned* __restrict__ dcK, unsigned* __restrict__ bcK,
    unsigned* __restrict__ subkey, float* __restrict__ out) {
    __shared__ __align__(16) float sHmax[IN_ROWS * SHP];
    __shared__ __align__(16) float sHmin[IN_ROWS * SHP];
    int blk = blockIdx.x;
    int b = blk >> 7;
    int tile = blk & 127;
    int tx0 = (tile & 7) << 6;
    int ty0 = (tile >> 3) << 5;
    int u = threadIdx.x;
    int half = u >> 7;      // 0: max map, 1: min map
    int v = u & 127;
    int rg = v >> 4;        // 0..7  (sub-chunk row group)
    int cg = v & 15;
    int vx = cg << 2;
    int vy = rg << 2;
    float4 acc[4];
    float ainit = half ? FINF : -FINF;
#pragma unroll
    for (int i = 0; i < 4; ++i) acc[i] = make_float4(ainit, ainit, ainit, ainit);

    for (int c = 0; c < NCH; ++c) {
        const float* xp = x + (((size_t)(b * NCH + c)) << 18);
        float* outp = out + (((size_t)(b * 4 + c)) << 18);
        // ---- h-pool direct from global: max AND min from the same loads ----
        for (int it = u; it < IN_ROWS * 16; it += 256) {
            int r = it >> 4;
            int x0 = (it & 15) << 2;
            int gy = ty0 - PAD + r;
            gy = gy < 0 ? 0 : (gy > H - 1 ? H - 1 : gy);
            const float* rowp = xp + (gy << 9);
            int gx0 = tx0 + x0;
            int aB = gx0 - 8; aB = aB < 0 ? 0 : aB;
            int bB = gx0 - 4; bB = bB < 0 ? 0 : bB;
            int dB = gx0 + 4; dB = dB > W - 4 ? W - 4 : dB;
            int eB = gx0 + 8; eB = eB > W - 4 ? W - 4 : eB;
            float4 fA = *(const float4*)(rowp + aB);
            float4 fB = *(const float4*)(rowp + bB);
            float4 fC = *(const float4*)(rowp + gx0);
            float4 fD = *(const float4*)(rowp + dB);
            float4 fE = *(const float4*)(rowp + eB);
            // x -> out copy (center float4 is raw x)
            if (r >= PAD && r < PAD + TH)
                *(float4*)&outp[((ty0 + r - PAD) << 9) + gx0] = fC;
            // core = cols gx0-4 .. gx0+7 (common to all 4 windows)
            float4 m4 = op4<true>(op4<true>(fB, fC), fD);
            float tmx = fmaxf(fmaxf(m4.x, m4.y), fmaxf(m4.z, m4.w));
            float4 n4 = op4<false>(op4<false>(fB, fC), fD);
            float tmn = fminf(fminf(n4.x, n4.y), fminf(n4.z, n4.w));
            *(float4*)&sHmax[r * SHP + x0] = make_float4(
                fmaxf(tmx, fmaxf(fA.y, fmaxf(fA.z, fA.w))),
                fmaxf(tmx, fmaxf(fA.z, fmaxf(fA.w, fE.x))),
                fmaxf(tmx, fmaxf(fA.w, fmaxf(fE.x, fE.y))),
                fmaxf(tmx, fmaxf(fE.x, fmaxf(fE.y, fE.z))));
            *(float4*)&sHmin[r * SHP + x0] = make_float4(
                fminf(tmn, fminf(fA.y, fminf(fA.z, fA.w))),
                fminf(tmn, fminf(fA.z, fminf(fA.w, fE.x))),
                fminf(tmn, fminf(fA.w, fminf(fE.x, fE.y))),
                fminf(tmn, fminf(fE.x, fminf(fE.y, fE.z))));
        }
        __syncthreads();
        // ---- v-pool, half-split ----
        int gbase = ((ty0 + vy) << 9) + tx0 + vx;
        if (half == 0) {
            float* vp = vmax + (((size_t)(b * NCH + c)) << 18);
            vpool_half<true, true>(sHmax, vy, vx, acc, vp, gbase);
        } else {
            vpool_half<false, false>(sHmin, vy, vx, acc, nullptr, 0);
        }
        __syncthreads();
    }
    // ---- per-pixel key maps + per-sub-chunk key maxima ----
    unsigned gb = ((unsigned)b << 18) + ((ty0 + vy) << 9) + tx0 + vx;
    if (half == 0) {
        float mn = FINF;
#pragma unroll
        for (int i = 0; i < 4; ++i) {
            float4 o = acc[i];
            *(uint4*)&bcK[gb + (i << 9)] =
                make_uint4(~mkey(o.x), ~mkey(o.y), ~mkey(o.z), ~mkey(o.w));
            mn = fminf(mn, fminf(fminf(o.x, o.y), fminf(o.z, o.w)));
        }
#pragma unroll
        for (int s = 1; s < 16; s <<= 1) mn = fminf(mn, __shfl_xor(mn, s));
        if (cg == 0) subkey[(BATCH + b) * NSUB + tile * 8 + rg] = ~mkey(mn);
    } else {
        float mx = -FINF;
#pragma unroll
        for (int i = 0; i < 4; ++i) {
            float4 o = acc[i];
            *(uint4*)&dcK[gb + (i << 9)] =
                make_uint4(mkey(o.x), mkey(o.y), mkey(o.z), mkey(o.w));
            mx = fmaxf(mx, fmaxf(fmaxf(o.x, o.y), fmaxf(o.z, o.w)));
        }
#pragma unroll
        for (int s = 1; s < 16; s <<= 1) mx = fmaxf(mx, __shfl_xor(mx, s));
        if (cg == 0) subkey[b * NSUB + tile * 8 + rg] = mkey(mx);
    }
}

// ---------------------------------------------------------------------------
// Screen + extract. 8 blocks per (map,batch) pair. Wave 0 of each block
// (redundantly, deterministically) computes tau = 26th-largest chunk key-max
// (chunk = 2048 px = 8 subs). Theorem: any global-top-26 element's sub-chunk
// has key-max >= tau. Qualifying subs (~26-40 of 1024) get exact 26-round
// (value,idx)-packed extraction, one wave per sub.
__global__ __launch_bounds__(256) void select_kernel(
    const unsigned* __restrict__ dcK, const unsigned* __restrict__ bcK,
    const unsigned* __restrict__ subkey, unsigned long long* __restrict__ cand,
    int* __restrict__ nQ) {
    int blk = blockIdx.x;       // 256 blocks
    int pair = blk >> 3;
    int bslot = blk & 7;
    int map = pair >> 4;
    int b = pair & 15;
    int t = threadIdx.x;
    int wv = t >> 6, lane = t & 63;
    __shared__ int sList[NSUB];
    __shared__ int sN;
    if (wv == 0) {
        const unsigned* sk = subkey + (size_t)pair * NSUB + lane * 16;
        unsigned k[16];
        *(uint4*)&k[0] = *(const uint4*)&sk[0];
        *(uint4*)&k[4] = *(const uint4*)&sk[4];
        *(uint4*)&k[8] = *(const uint4*)&sk[8];
        *(uint4*)&k[12] = *(const uint4*)&sk[12];
        unsigned c0 = k[0], c1 = k[8];
#pragma unroll
        for (int j = 1; j < 8; ++j) { c0 = max(c0, k[j]); c1 = max(c1, k[8 + j]); }
        unsigned long long q0 = ((unsigned long long)c0 << 32) | (unsigned)(lane * 2);
        unsigned long long q1 = ((unsigned long long)c1 << 32) | (unsigned)(lane * 2 + 1);
        unsigned tau = 0;
        for (int r = 0; r < K; ++r) {
            unsigned long long m = q0 > q1 ? q0 : q1;
#pragma unroll
            for (int s = 1; s < 64; s <<= 1) {
                unsigned long long o = shfl_xor_u64(m, s);
                m = o > m ? o : m;
            }
            if (r == K - 1) tau = (unsigned)(m >> 32);
            if (q0 == m) q0 = 0;
            if (q1 == m) q1 = 0;
        }
        int base = 0;
        for (int j = 0; j < 16; ++j) {
            bool q = k[j] >= tau;
            unsigned long long mk = __ballot(q);
            if (q) sList[base + __popcll(mk & ((1ull << lane) - 1ull))] = lane * 16 + j;
            base += (int)__popcll(mk);
        }
        if (lane == 0) {
            sN = base;
            if (bslot == 0) nQ[pair] = base;
        }
    }
    __syncthreads();
    int n = sN;
    const unsigned* mapK = (map ? bcK : dcK) + ((size_t)b << 18);
    for (int s_i = bslot * 4 + wv; s_i < n; s_i += 32) {
        int sub = sList[s_i];
        int stile = sub >> 3, srg = sub & 7;
        int tx0 = (stile & 7) << 6;
        int ys = ((stile >> 3) << 5) + srg * 4;
        unsigned long long kk[4];
#pragma unroll
        for (int j = 0; j < 4; ++j) {
            int p = ((ys + j) << 9) + tx0 + lane;
            kk[j] = ((unsigned long long)mapK[p] << 32) | (unsigned)(0x7FFFFFFF - p);
        }
        unsigned long long* cp = cand + (size_t)pair * CAND_STRIDE + s_i * K;
        for (int r = 0; r < K; ++r) {
            unsigned long long m01 = kk[0] > kk[1] ? kk[0] : kk[1];
            unsigned long long m23 = kk[2] > kk[3] ? kk[2] : kk[3];
            unsigned long long m = m01 > m23 ? m01 : m23;
#pragma unroll
            for (int s = 1; s < 64; s <<= 1) {
                unsigned long long o = shfl_xor_u64(m, s);
                m = o > m ? o : m;
            }
            if (lane == 0) cp[r] = m;
#pragma unroll
            for (int j = 0; j < 4; ++j)
                if (kk[j] == m) kk[j] = 0;
        }
    }
}

// ---------------------------------------------------------------------------
// Per-(map,batch) merge of n*26 candidates -> global top-26 (sorted order).
// map0 (dc): A1 (argmax of per-pixel channel max, first occurrence).
// map1 (bc): the 26 indices for A2.
__global__ __launch_bounds__(256) void merge_kernel(
    const unsigned long long* __restrict__ cand, const int* __restrict__ nQ,
    const float* __restrict__ img, float* __restrict__ A1, int* __restrict__ idx2all) {
    int pair = blockIdx.x;
    int map = pair >> 4, b = pair & 15;
    int t = threadIdx.x;
    int wv = t >> 6, lane = t & 63;
    int C = nQ[pair] * K;
    const unsigned long long* cp = cand + (size_t)pair * CAND_STRIDE;
    __shared__ unsigned long long sB[4];
    __shared__ unsigned long long sWin[K];
    __shared__ unsigned long long sCarry[K];
    __shared__ float sM[K];
    int ntile = (C + 1663) / 1664;
    for (int tile = 0; tile < ntile; ++tile) {
        int lo = tile * 1664;
        int hi = C < lo + 1664 ? C : lo + 1664;
        unsigned long long kk[7], kc;
#pragma unroll
        for (int q = 0; q < 7; ++q) {
            int idx = lo + q * 256 + t;
            kk[q] = (idx < hi) ? cp[idx] : 0ull;
        }
        kc = (tile > 0 && t < K) ? sCarry[t] : 0ull;
        __syncthreads();
        for (int r = 0; r < K; ++r) {
            unsigned long long m = kc;
#pragma unroll
            for (int q = 0; q < 7; ++q)
                if (kk[q] > m) m = kk[q];
#pragma unroll
            for (int s = 1; s < 64; s <<= 1) {
                unsigned long long o = shfl_xor_u64(m, s);
                m = o > m ? o : m;
            }
            if (lane == 0) sB[wv] = m;
            __syncthreads();
            unsigned long long wb = sB[0];
            if (sB[1] > wb) wb = sB[1];
            if (sB[2] > wb) wb = sB[2];
            if (sB[3] > wb) wb = sB[3];
            if (t == 0) sWin[r] = wb;
#pragma unroll
            for (int q = 0; q < 7; ++q)
                if (kk[q] == wb) kk[q] = 0;
            if (kc == wb) kc = 0;
            __syncthreads();
        }
        if (tile + 1 < ntile) {
            if (t < K) sCarry[t] = sWin[t];
            __syncthreads();
        }
    }
    if (map == 0) {
        if (t < K) {
            int p = 0x7FFFFFFF - (int)(unsigned)(sWin[t] & 0xFFFFFFFFull);
            float m = img[(((size_t)(b * NCH + 0)) << 18) + p];
            m = fmaxf(m, img[(((size_t)(b * NCH + 1)) << 18) + p]);
            m = fmaxf(m, img[(((size_t)(b * NCH + 2)) << 18) + p]);
            sM[t] = m;
        }
        __syncthreads();
        if (t == 0) {
            float bm = -FINF;
            int bj = 0;
            for (int j = 0; j < K; ++j)
                if (sM[j] > bm) { bm = sM[j]; bj = j; }   // strict > = first occurrence
            int p = 0x7FFFFFFF - (int)(unsigned)(sWin[bj] & 0xFFFFFFFFull);
#pragma unroll
            for (int c = 0; c < NCH; ++c)
                A1[b * NCH + c] = img[(((size_t)(b * NCH + c)) << 18) + p];
        }
    } else {
        if (t < K)
            idx2all[b * K + t] = 0x7FFFFFFF - (int)(unsigned)(sWin[t] & 0xFFFFFFFFull);
    }
}

// ---------------------------------------------------------------------------
// A2 (mean over ALL batches' bottom-k indices — faithful to the reference's
// batch-mixing bug), A = 0.75*A1 + 0.25*A2, d = (1 - A) + 1e-6
__global__ __launch_bounds__(256) void compute_A_kernel(
    const float* __restrict__ img, const int* __restrict__ idx2all,
    const float* __restrict__ A1, float* __restrict__ dvec) {
    int b = blockIdx.x;
    __shared__ float ssum[256];
    for (int c = 0; c < NCH; ++c) {
        float s = 0.0f;
        for (int j = threadIdx.x; j < BK; j += 256)
            s += img[(((size_t)(b * NCH + c)) << 18) + idx2all[j]];
        ssum[threadIdx.x] = s;
        __syncthreads();
        for (int st = 128; st > 0; st >>= 1) {
            if (threadIdx.x < st) ssum[threadIdx.x] += ssum[threadIdx.x + st];
            __syncthreads();
        }
        if (threadIdx.x == 0) {
            float A2 = ssum[0] / (float)BK;
            float A = 0.75f * A1[b * NCH + c] + 0.25f * A2;
            dvec[b * NCH + c] = (1.0f - A) + 1e-6f;
        }
        __syncthreads();
    }
}

// ---------------------------------------------------------------------------
// t = 1 - 0.95 * min_c (1 - Vmax_c)/d_c   (x-channels already written by pool)
__global__ __launch_bounds__(256) void final_t_kernel(
    const float* __restrict__ vmax, const float* __restrict__ dvec,
    float* __restrict__ out) {
    int i4 = (blockIdx.x * 256 + threadIdx.x) << 2;
    int b = i4 >> 18;
    int p = i4 & (HW - 1);
    const float* vp = vmax + (((size_t)(b * NCH)) << 18) + p;
    float r0 = 1.0f / dvec[b * NCH + 0];
    float r1 = 1.0f / dvec[b * NCH + 1];
    float r2 = 1.0f / dvec[b * NCH + 2];
    float4 v0 = *(const float4*)(vp);
    float4 v1 = *(const float4*)(vp + ((size_t)1 << 18));
    float4 v2 = *(const float4*)(vp + ((size_t)2 << 18));
    float4 t;
    t.x = 1.0f - 0.95f * fminf(fminf((1.0f - v0.x) * r0, (1.0f - v1.x) * r1), (1.0f - v2.x) * r2);
    t.y = 1.0f - 0.95f * fminf(fminf((1.0f - v0.y) * r0, (1.0f - v1.y) * r1), (1.0f - v2.y) * r2);
    t.z = 1.0f - 0.95f * fminf(fminf((1.0f - v0.z) * r0, (1.0f - v1.z) * r1), (1.0f - v2.z) * r2);
    t.w = 1.0f - 0.95f * fminf(fminf((1.0f - v0.w) * r0, (1.0f - v1.w) * r1), (1.0f - v2.w) * r2);
    *(float4*)&out[(((size_t)(b * 4 + 3)) << 18) + p] = t;
}

// ---------------------------------------------------------------------------
extern "C" void kernel_launch(void* const* d_in, const int* in_sizes, int n_in,
                              void* d_out, int out_size, void* d_ws, size_t ws_size,
                              hipStream_t stream) {
    const float* x = (const float*)d_in[0];
    float* out = (float*)d_out;

    const size_t nCh = (size_t)BATCH * NCH * HW; // 12,582,912
    const size_t nPix = (size_t)BATCH * HW;      //  4,194,304

    float* ws = (float*)d_ws;
    float* Vmax = ws;
    unsigned* dcK = (unsigned*)(Vmax + nCh);
    unsigned* bcK = dcK + nPix;
    unsigned* subkey = bcK + nPix;                       // [2][16][1024]
    unsigned long long* cand =
        (unsigned long long*)(subkey + (size_t)2 * BATCH * NSUB);
    int* nQ = (int*)(cand + (size_t)NPAIR * CAND_STRIDE);
    float* A1 = (float*)(nQ + NPAIR);
    int* idx2all = (int*)(A1 + BATCH * NCH);
    float* dvec = (float*)(idx2all + BK);

    pool_kernel<<<BATCH * 128, 256, 0, stream>>>(x, Vmax, dcK, bcK, subkey, out);
    select_kernel<<<NPAIR * 8, 256, 0, stream>>>(dcK, bcK, subkey, cand, nQ);
    merge_kernel<<<NPAIR, 256, 0, stream>>>(cand, nQ, x, A1, idx2all);
    compute_A_kernel<<<BATCH, 256, 0, stream>>>(x, idx2all, A1, dvec);
    final_t_kernel<<<(int)(nPix / 4 / 256), 256, 0, stream>>>(Vmax, dvec, out);
}